// Round 24
// baseline (1783.827 us; speedup 1.0000x reference)
//
#include <hip/hip_runtime.h>
#include <hip/hip_bf16.h>

#define B_N 4096
#define L_N 32
#define C_N 28
#define H_N 512
#define T_N 32
#define G_N 2048
// K layout (chunks of 32): A: [0..15]=h_hi, [16]=ctx_hi, [17..32]=h_lo, [33]=ctx_lo
// W store: [0..16]=W_hi, [17..33]=W_lo.  MFMA chunks: 51 =
//   kc<17: A[kc](hi) x Whi[kc];  17<=kc<34: A[kc](lo) x Whi[kc-17];  34<=kc<51: A[kc-34](hi) x Wlo[kc-17]
#define CHA 34
#define CHSH 4096          // shorts per frag chunk: 8 tiles * 64 lanes * 8
#define ABLK (CHA * CHSH)  // shorts per 128-row A block / per 128-col W block
#define XS 29              // padded LDS stride for prep_x (29 coprime 32)

typedef __attribute__((ext_vector_type(4))) float f32x4;
typedef __attribute__((ext_vector_type(8))) short s16x8;

static constexpr size_t OFF_WF = 0;                                    // Wf bf16 16*ABLK
static constexpr size_t AB_ONE = (size_t)32 * ABLK * 2;                // 8.9 MB
static constexpr size_t OFF_AB = OFF_WF + (size_t)16 * ABLK * 2;
static constexpr size_t OFF_X  = OFF_AB + 2 * AB_ONE;                  // f32 [4096][32][28]
static constexpr size_t OFF_UA = OFF_X + (size_t)B_N * L_N * C_N * 4;  // f32 [4096][32]
static constexpr size_t OFF_BS = OFF_UA + (size_t)B_N * L_N * 4;       // f32 [2048]
static constexpr size_t OFF_AC = OFF_BS + 8192;                        // accW, accO
static constexpr size_t OFF_CS = OFF_AC + 32768;                       // f32 [4096][512]
static constexpr size_t WS_NEED = OFF_CS + (size_t)B_N * H_N * 4;      // ~35 MB

__device__ __forceinline__ float bf2f(short s) {
    union { unsigned int u; float f; } v;
    v.u = ((unsigned int)(unsigned short)s) << 16;
    return v.f;
}
__device__ __forceinline__ short bfbits(__hip_bfloat16 b) {
    union { __hip_bfloat16 b; short s; } v; v.b = b; return v.s;
}
__device__ __forceinline__ float sigmoidf_(float x) { return 1.f / (1.f + __expf(-x)); }
__device__ __forceinline__ float tanhf_(float x) {
    float ax = fabsf(x), e = __expf(-2.f * ax);
    float t = (1.f - e) / (1.f + e);
    return x < 0.f ? -t : t;
}

__global__ __launch_bounds__(256) void fill_out(float* out, float v) {
    int i = blockIdx.x * 256 + threadIdx.x;
    if (i < B_N * 32) out[i] = v;
}

// ---------------- prep_x: LDS slab with padded stride (conflict-free) ----------------
__global__ __launch_bounds__(256) void prep_x(const float* __restrict__ input,
                       const float* __restrict__ mask,
                       const float* __restrict__ w1, const float* __restrict__ b1,
                       const float* __restrict__ cw, const float* __restrict__ cb,
                       float* __restrict__ x, float* __restrict__ ua)
{
    __shared__ float sw1[C_N * C_N * 3];
    __shared__ float sb1[C_N], scw[C_N];
    __shared__ float sin[8 * L_N * XS];           // padded slab
    __shared__ float sxb[8 * L_N * XS];
    for (int i = threadIdx.x; i < C_N * C_N * 3; i += 256) sw1[i] = w1[i];
    if (threadIdx.x < C_N) { sb1[threadIdx.x] = b1[threadIdx.x]; scw[threadIdx.x] = cw[threadIdx.x]; }
    const float* src = input + (size_t)blockIdx.x * (8 * L_N * C_N);
    for (int i = threadIdx.x; i < 8 * L_N * C_N; i += 256) {
        int lr = i / (L_N * C_N);
        int rem = i - lr * (L_N * C_N);
        int l = rem / C_N, c = rem - l * C_N;
        sin[lr * (L_N * XS) + l * XS + c] = src[i];
    }
    __syncthreads();

    int idx = blockIdx.x * 256 + threadIdx.x;     // global (b,l)
    int l = idx & 31;
    int wv = threadIdx.x >> 5;
    const float* inb = sin + wv * (L_N * XS);
    float m = mask[idx];
    float uacc = 0.f;
    for (int o = 0; o < C_N; ++o) {
        float y = sb1[o];
        const float* wo = sw1 + o * (C_N * 3);
        for (int i = 0; i < C_N; ++i) {
            float xm1 = (l > 0)  ? inb[(l - 1) * XS + i] : 0.f;
            float x0  = inb[l * XS + i];
            float xp1 = (l < 31) ? inb[(l + 1) * XS + i] : 0.f;
            y += wo[i * 3 + 0] * xm1 + wo[i * 3 + 1] * x0 + wo[i * 3 + 2] * xp1;
        }
        y *= m;
        float e = (y > 0.f) ? y : (__expf(y) - 1.f);
        float xv = e + inb[l * XS + o];
        sxb[wv * (L_N * XS) + l * XS + o] = xv;
        uacc += xv * scw[o];
    }
    ua[idx] = (uacc + cb[0]) * m;
    __syncthreads();
    float* xdst = x + (size_t)blockIdx.x * (8 * L_N * C_N);
    for (int i = threadIdx.x; i < 8 * L_N * C_N; i += 256) {
        int lr = i / (L_N * C_N);
        int rem = i - lr * (L_N * C_N);
        int l2 = rem / C_N, c = rem - l2 * C_N;
        xdst[i] = sxb[lr * (L_N * XS) + l2 * XS + c];
    }
}

// ---------------- prep_wf: frag-major hi/lo weights ----------------
__global__ __launch_bounds__(256) void prep_wf(const float* __restrict__ w_ih,
                                               const float* __restrict__ w_hh,
                                               short* __restrict__ Wf)
{
    int blk = blockIdx.x;                  // 16*34
    int n128 = blk / CHA, c = blk % CHA;
    bool lo = (c >= 17);
    int kbase = (lo ? (c - 17) : c) * 32;
    short* dst = Wf + ((size_t)n128 * CHA + c) * CHSH;
    for (int g = threadIdx.x; g < 512; g += 256) {
        int j = g >> 6, lane = g & 63;
        int p = n128 * 128 + j * 16 + (lane & 15);
        int unit = p >> 2, gate = p & 3;
        int srow = gate * H_N + unit;
        int kg = lane >> 4;
        s16x8 out;
        #pragma unroll
        for (int b2 = 0; b2 < 8; ++b2) {
            int k = kbase + kg * 8 + b2;
            float v = 0.f;
            if (k < 512) v = w_hh[(size_t)srow * H_N + k];
            else if (k < 540) v = w_ih[srow * C_N + (k - 512)];
            __hip_bfloat16 hi = __float2bfloat16(v);
            if (lo) out[b2] = bfbits(__float2bfloat16(v - __bfloat162float(hi)));
            else    out[b2] = bfbits(hi);
        }
        *(s16x8*)(dst + g * 8) = out;
    }
}

__global__ void prep_bs(const float* __restrict__ b_ih, const float* __restrict__ b_hh,
                        float* __restrict__ bsum)
{
    int p = blockIdx.x * 256 + threadIdx.x;
    if (p < G_N) {
        int unit = p >> 2, gate = p & 3;
        bsum[p] = b_ih[gate * H_N + unit] + b_hh[gate * H_N + unit];
    }
}

__global__ void prep_zero(unsigned int* __restrict__ a32, float* __restrict__ cst,
                          float* __restrict__ acc)
{
    int idx = blockIdx.x * blockDim.x + threadIdx.x;
    if (idx < B_N * 1088) a32[idx] = 0u;
    if (idx < B_N * H_N) cst[idx] = 0.f;
    if (idx < 2 * B_N) acc[idx] = 0.f;
}

// ---------------- params ----------------
struct RParams {
    const float* mask;
    const float* bias_mat;
    const float* fc1_w;
    const float* fc1_b;
    const float* conv2_w;
    const float* conv2_b;
    const short* Wf;
    const short* Ain;
    short* Aout;
    const float* x;
    const float* ua;
    const float* bsum;
    float* accW;
    float* accO;
    float* cstate;
    float* out;
};

// ---------------- ctx_step ----------------
__global__ __launch_bounds__(256) void ctx_step(RParams P, int t)
{
    const int lane = threadIdx.x & 63;
    const int wave = threadIdx.x >> 6;
    const int row  = blockIdx.x * 4 + wave;

    float aW = P.accW[row];
    float aO = P.accO[row];
    if (t > 0 && lane == 0)
        P.out[row * T_N + (t - 1)] = (aO + P.conv2_b[0]) * P.mask[row * L_N + (t - 1)];

    if (t < T_N) {
        if (lane == 0) { P.accW[row] = 0.f; P.accO[row] = 0.f; }
        float w_a = aW + P.fc1_b[0];
        int l32 = lane & 31;
        float e = P.ua[row * L_N + l32] + w_a;
        e = (e > 0.f) ? e : 0.01f * e;
        e += P.bias_mat[row * L_N + l32];
        float mx = e;
        #pragma unroll
        for (int off = 16; off > 0; off >>= 1) mx = fmaxf(mx, __shfl_xor(mx, off, 32));
        float pexp = __expf(e - mx);
        float ssum = pexp;
        #pragma unroll
        for (int off = 16; off > 0; off >>= 1) ssum += __shfl_xor(ssum, off, 32);
        float p = pexp / ssum;
        int cc = (lane < C_N) ? lane : 0;
        const float* xrow = P.x + (size_t)row * (L_N * C_N) + cc;
        float ctx = 0.f;
        #pragma unroll
        for (int l = 0; l < L_N; ++l) {
            float al = __shfl(p, l);
            ctx += al * xrow[l * C_N];
        }
        if (lane < C_N) {
            int m128 = row >> 7, mt = (row & 127) >> 4, r = row & 15;
            int flane = r + 16 * (lane >> 3);
            short* base = P.Aout + (size_t)m128 * ABLK + mt * 512 + flane * 8 + (lane & 7);
            __hip_bfloat16 hi = __float2bfloat16(ctx);
            base[16 * CHSH] = bfbits(hi);
            base[33 * CHSH] = bfbits(__float2bfloat16(ctx - __bfloat162float(hi)));
        }
    }
}

// ---------------- gemm_cell_step: M=64 blocks (grid 1024), 3 blocks/CU ----------------
__global__ __launch_bounds__(256, 3) void gemm_cell_step(RParams P)
{
    __shared__ __align__(16) char smem[24576];   // gates 16KB @0; hasm 8KB @16384

    const int tid  = threadIdx.x;
    const int lane = tid & 63;
    const int wave = tid >> 6;
    const int bid  = blockIdx.x;       // 1024
    // XCD swizzle: each XCD (bid&7) owns a 16m x 8n sub-grid
    const int xg = bid & 7, gg = bid >> 3;      // gg 0..127
    const int m64 = (xg >> 1) * 16 + (gg & 15); // 0..63
    const int n   = (xg & 1) * 8 + (gg >> 4);   // 0..15
    const int m128 = m64 >> 1, half = m64 & 1;
    const int wm = wave >> 1, wn = wave & 1;

    const short* Af = P.Ain + (size_t)m128 * ABLK;
    const short* Wg = P.Wf  + (size_t)n * ABLK;
    const short* aB[2];
    const short* wB[4];
    #pragma unroll
    for (int i = 0; i < 2; ++i)
        aB[i] = Af + ((half * 4 + wm * 2 + i) * 64 + lane) * 8;
    #pragma unroll
    for (int j = 0; j < 4; ++j)
        wB[j] = Wg + ((wn * 4 + j) * 64 + lane) * 8;

    f32x4 acc[2][4];
    #pragma unroll
    for (int i = 0; i < 2; ++i)
        #pragma unroll
        for (int j = 0; j < 4; ++j)
            acc[i][j] = (f32x4){0.f, 0.f, 0.f, 0.f};

    s16x8 a0[2], w0[4], a1[2], w1[4];
    auto ldc = [&](int kc, s16x8 (&A)[2], s16x8 (&W)[4]) {
        int ka = (kc < CHA) ? kc : kc - CHA;
        int kw = (kc < 17) ? kc : kc - 17;
        #pragma unroll
        for (int i = 0; i < 2; ++i) A[i] = *(const s16x8*)(aB[i] + ka * CHSH);
        #pragma unroll
        for (int j = 0; j < 4; ++j) W[j] = *(const s16x8*)(wB[j] + kw * CHSH);
    };
    auto domm = [&](s16x8 (&A)[2], s16x8 (&W)[4]) {
        #pragma unroll
        for (int i = 0; i < 2; ++i)
            #pragma unroll
            for (int j = 0; j < 4; ++j)
                acc[i][j] = __builtin_amdgcn_mfma_f32_16x16x32_bf16(A[i], W[j], acc[i][j], 0, 0, 0);
    };

    ldc(0, a0, w0); ldc(1, a1, w1);
    __builtin_amdgcn_sched_barrier(0);
    for (int kc = 0; kc < 51; kc += 2) {
        domm(a0, w0); if (kc + 2 < 51) ldc(kc + 2, a0, w0);
        __builtin_amdgcn_sched_barrier(0);
        if (kc + 1 < 51) {
            domm(a1, w1); if (kc + 3 < 51) ldc(kc + 3, a1, w1);
            __builtin_amdgcn_sched_barrier(0);
        }
    }

    // ---- epilogue: gates(64x64 per hh) -> cell -> h frag assembly -> store + dots ----
    __syncthreads();
    float* gates = (float*)smem;                   // 64 x 64 f32 = 16 KB
    short* hasm  = (short*)(smem + 16384);         // hi 4KB + lo 4KB
    #pragma unroll
    for (int hh = 0; hh < 2; ++hh) {
        if (wn == hh) {
            #pragma unroll
            for (int i = 0; i < 2; ++i)
                #pragma unroll
                for (int j = 0; j < 4; ++j)
                    #pragma unroll
                    for (int r = 0; r < 4; ++r) {
                        int rowl = wm * 32 + i * 16 + (lane >> 4) * 4 + r;
                        int coll = j * 16 + (lane & 15);
                        gates[rowl * 64 + coll] = acc[i][j][r];
                    }
        }
        __syncthreads();
        {
            int u = tid & 15, rr = tid >> 4;       // unit-local, row-thread (16 rows)
            int unit = n * 32 + hh * 16 + u;
            f32x4 bsv = *(const f32x4*)(P.bsum + unit * 4);
            float f1v = P.fc1_w[unit];
            float c2v = P.conv2_w[unit];
            int kg = hh * 2 + (u >> 3);
            #pragma unroll
            for (int it = 0; it < 4; ++it) {
                int rowl = it * 16 + rr;
                int grow = m64 * 64 + rowl;
                f32x4 gv = *(const f32x4*)(gates + rowl * 64 + u * 4);
                float pi = gv.x + bsv.x;
                float pf = gv.y + bsv.y;
                float pg = gv.z + bsv.z;
                float po = gv.w + bsv.w;
                float* cp = P.cstate + (size_t)grow * H_N + unit;
                float c = sigmoidf_(pf) * (*cp) + sigmoidf_(pi) * tanhf_(pg);
                *cp = c;
                float h = sigmoidf_(po) * tanhf_(c);
                __hip_bfloat16 hi = __float2bfloat16(h);
                // hasm: [tile it][lane rr+16*kg][elem u&7]
                hasm[it * 512 + (rr + 16 * kg) * 8 + (u & 7)]        = bfbits(hi);
                hasm[2048 + it * 512 + (rr + 16 * kg) * 8 + (u & 7)] = bfbits(__float2bfloat16(h - __bfloat162float(hi)));
                float wd = f1v * h, od = c2v * h;
                #pragma unroll
                for (int off = 8; off > 0; off >>= 1) {
                    wd += __shfl_xor(wd, off);
                    od += __shfl_xor(od, off);
                }
                if (u == 0) {
                    atomicAdd(P.accW + grow, wd);
                    atomicAdd(P.accO + grow, od);
                }
            }
        }
        __syncthreads();
    }
    // coalesced frag store: block covers tiles [half*4, half*4+4) of chunk n (hi) / 17+n (lo)
    short* dhi = P.Aout + (size_t)m128 * ABLK + (size_t)n * CHSH + half * 4 * 512;
    short* dlo = P.Aout + (size_t)m128 * ABLK + (size_t)(17 + n) * CHSH + half * 4 * 512;
    *(s16x8*)(dhi + tid * 8) = *(const s16x8*)(hasm + tid * 8);          // 2048 shorts
    *(s16x8*)(dlo + tid * 8) = *(const s16x8*)(hasm + 2048 + tid * 8);
}

extern "C" void kernel_launch(void* const* d_in, const int* in_sizes, int n_in,
                              void* d_out, int out_size, void* d_ws, size_t ws_size,
                              hipStream_t stream)
{
    float* out = (float*)d_out;
    if (ws_size < WS_NEED) { fill_out<<<512, 256, 0, stream>>>(out, 4000.f); return; }

    const float* input = (const float*)d_in[0];
    const float* mask  = (const float*)d_in[1];
    const float* biasm = (const float*)d_in[2];
    const float* w1    = (const float*)d_in[3];
    const float* b1    = (const float*)d_in[4];
    const float* cw    = (const float*)d_in[5];
    const float* cb    = (const float*)d_in[6];
    const float* w_ih  = (const float*)d_in[7];
    const float* w_hh  = (const float*)d_in[8];
    const float* b_ih  = (const float*)d_in[9];
    const float* b_hh  = (const float*)d_in[10];
    const float* fc1w  = (const float*)d_in[11];
    const float* fc1b  = (const float*)d_in[12];
    const float* c2w   = (const float*)d_in[13];
    const float* c2b   = (const float*)d_in[14];

    char* ws = (char*)d_ws;
    short* Wf = (short*)(ws + OFF_WF);
    short* A0 = (short*)(ws + OFF_AB);
    short* A1 = (short*)(ws + OFF_AB + AB_ONE);
    float* x    = (float*)(ws + OFF_X);
    float* ua   = (float*)(ws + OFF_UA);
    float* bsum = (float*)(ws + OFF_BS);
    float* accW = (float*)(ws + OFF_AC);
    float* accO = (float*)(ws + OFF_AC + 16384);
    float* cst  = (float*)(ws + OFF_CS);

    prep_x<<<(B_N * L_N) / 256, 256, 0, stream>>>(input, mask, w1, b1, cw, cb, x, ua);
    prep_wf<<<16 * CHA, 256, 0, stream>>>(w_ih, w_hh, Wf);
    prep_bs<<<(G_N + 255) / 256, 256, 0, stream>>>(b_ih, b_hh, bsum);
    prep_zero<<<(B_N * 1088 + 255) / 256, 256, 0, stream>>>((unsigned int*)A0, cst, accW);

    RParams P;
    P.mask = mask; P.bias_mat = biasm; P.fc1_w = fc1w; P.fc1_b = fc1b;
    P.conv2_w = c2w; P.conv2_b = c2b; P.Wf = Wf;
    P.x = x; P.ua = ua; P.bsum = bsum; P.accW = accW; P.accO = accO;
    P.cstate = cst; P.out = out;

    short* bufs[2] = { A0, A1 };
    for (int t = 0; t < T_N; ++t) {
        P.Ain  = bufs[t & 1];
        P.Aout = bufs[t & 1];
        ctx_step<<<B_N / 4, 256, 0, stream>>>(P, t);
        P.Ain  = bufs[t & 1];
        P.Aout = bufs[(t + 1) & 1];
        gemm_cell_step<<<1024, 256, 0, stream>>>(P);
    }
    P.Ain = bufs[T_N & 1];
    P.Aout = bufs[T_N & 1];
    ctx_step<<<B_N / 4, 256, 0, stream>>>(P, T_N);
}

// Round 25
// 1614.820 us; speedup vs baseline: 1.1047x; 1.1047x over previous
//
#include <hip/hip_runtime.h>
#include <hip/hip_bf16.h>

#define B_N 4096
#define L_N 32
#define C_N 28
#define H_N 512
#define T_N 32
#define G_N 2048
// K layout (chunks of 32): A: [0..15]=h_hi, [16]=ctx_hi, [17..32]=h_lo, [33]=ctx_lo
// W store: [0..16]=W_hi, [17..33]=W_lo.  MFMA chunks: 51.
#define CHA 34
#define CHSH 4096          // shorts per frag chunk: 8 tiles * 64 lanes * 8
#define ABLK (CHA * CHSH)
#define XS 29              // padded LDS stride for prep_x

typedef __attribute__((ext_vector_type(4))) float f32x4;
typedef __attribute__((ext_vector_type(8))) short s16x8;

static constexpr size_t OFF_WF = 0;                                    // Wf bf16 16*ABLK
static constexpr size_t AB_ONE = (size_t)32 * ABLK * 2;                // 8.9 MB
static constexpr size_t OFF_AB = OFF_WF + (size_t)16 * ABLK * 2;
static constexpr size_t OFF_X  = OFF_AB + 2 * AB_ONE;                  // f32 [4096][32][28]
static constexpr size_t OFF_UA = OFF_X + (size_t)B_N * L_N * C_N * 4;  // f32 [4096][32]
static constexpr size_t OFF_BS = OFF_UA + (size_t)B_N * L_N * 4;       // f32 [2048]
static constexpr size_t OFF_AC = OFF_BS + 8192;                        // accW[32][4096], accO[32][4096]
static constexpr size_t ACC_HALF = (size_t)32 * B_N * 4;               // 512 KB
static constexpr size_t OFF_CS = OFF_AC + 2 * ACC_HALF;                // f32 [4096][512]
static constexpr size_t WS_NEED = OFF_CS + (size_t)B_N * H_N * 4;      // ~36 MB

__device__ __forceinline__ short bfbits(__hip_bfloat16 b) {
    union { __hip_bfloat16 b; short s; } v; v.b = b; return v.s;
}
__device__ __forceinline__ float sigmoidf_(float x) { return 1.f / (1.f + __expf(-x)); }
__device__ __forceinline__ float tanhf_(float x) {
    float ax = fabsf(x), e = __expf(-2.f * ax);
    float t = (1.f - e) / (1.f + e);
    return x < 0.f ? -t : t;
}

__global__ __launch_bounds__(256) void fill_out(float* out, float v) {
    int i = blockIdx.x * 256 + threadIdx.x;
    if (i < B_N * 32) out[i] = v;
}

// ---------------- prep_x: LDS slab, padded stride 29 (conflict-free) ----------------
__global__ __launch_bounds__(256) void prep_x(const float* __restrict__ input,
                       const float* __restrict__ mask,
                       const float* __restrict__ w1, const float* __restrict__ b1,
                       const float* __restrict__ cw, const float* __restrict__ cb,
                       float* __restrict__ x, float* __restrict__ ua)
{
    __shared__ float sw1[C_N * C_N * 3];
    __shared__ float sb1[C_N], scw[C_N];
    __shared__ float sin[8 * L_N * XS];
    __shared__ float sxb[8 * L_N * XS];
    for (int i = threadIdx.x; i < C_N * C_N * 3; i += 256) sw1[i] = w1[i];
    if (threadIdx.x < C_N) { sb1[threadIdx.x] = b1[threadIdx.x]; scw[threadIdx.x] = cw[threadIdx.x]; }
    const float* src = input + (size_t)blockIdx.x * (8 * L_N * C_N);
    for (int i = threadIdx.x; i < 8 * L_N * C_N; i += 256) {
        int lr = i / (L_N * C_N);
        int rem = i - lr * (L_N * C_N);
        int l = rem / C_N, c = rem - l * C_N;
        sin[lr * (L_N * XS) + l * XS + c] = src[i];
    }
    __syncthreads();

    int idx = blockIdx.x * 256 + threadIdx.x;
    int l = idx & 31;
    int wv = threadIdx.x >> 5;
    const float* inb = sin + wv * (L_N * XS);
    float m = mask[idx];
    float uacc = 0.f;
    for (int o = 0; o < C_N; ++o) {
        float y = sb1[o];
        const float* wo = sw1 + o * (C_N * 3);
        for (int i = 0; i < C_N; ++i) {
            float xm1 = (l > 0)  ? inb[(l - 1) * XS + i] : 0.f;
            float x0  = inb[l * XS + i];
            float xp1 = (l < 31) ? inb[(l + 1) * XS + i] : 0.f;
            y += wo[i * 3 + 0] * xm1 + wo[i * 3 + 1] * x0 + wo[i * 3 + 2] * xp1;
        }
        y *= m;
        float e = (y > 0.f) ? y : (__expf(y) - 1.f);
        float xv = e + inb[l * XS + o];
        sxb[wv * (L_N * XS) + l * XS + o] = xv;
        uacc += xv * scw[o];
    }
    ua[idx] = (uacc + cb[0]) * m;
    __syncthreads();
    float* xdst = x + (size_t)blockIdx.x * (8 * L_N * C_N);
    for (int i = threadIdx.x; i < 8 * L_N * C_N; i += 256) {
        int lr = i / (L_N * C_N);
        int rem = i - lr * (L_N * C_N);
        int l2 = rem / C_N, c = rem - l2 * C_N;
        xdst[i] = sxb[lr * (L_N * XS) + l2 * XS + c];
    }
}

// ---------------- prep_wf: frag-major hi/lo weights ----------------
__global__ __launch_bounds__(256) void prep_wf(const float* __restrict__ w_ih,
                                               const float* __restrict__ w_hh,
                                               short* __restrict__ Wf)
{
    int blk = blockIdx.x;                  // 16*34
    int n128 = blk / CHA, c = blk % CHA;
    bool lo = (c >= 17);
    int kbase = (lo ? (c - 17) : c) * 32;
    short* dst = Wf + ((size_t)n128 * CHA + c) * CHSH;
    for (int g = threadIdx.x; g < 512; g += 256) {
        int j = g >> 6, lane = g & 63;
        int p = n128 * 128 + j * 16 + (lane & 15);
        int unit = p >> 2, gate = p & 3;
        int srow = gate * H_N + unit;
        int kg = lane >> 4;
        s16x8 out;
        #pragma unroll
        for (int b2 = 0; b2 < 8; ++b2) {
            int k = kbase + kg * 8 + b2;
            float v = 0.f;
            if (k < 512) v = w_hh[(size_t)srow * H_N + k];
            else if (k < 540) v = w_ih[srow * C_N + (k - 512)];
            __hip_bfloat16 hi = __float2bfloat16(v);
            if (lo) out[b2] = bfbits(__float2bfloat16(v - __bfloat162float(hi)));
            else    out[b2] = bfbits(hi);
        }
        *(s16x8*)(dst + g * 8) = out;
    }
}

__global__ void prep_bs(const float* __restrict__ b_ih, const float* __restrict__ b_hh,
                        float* __restrict__ bsum)
{
    int p = blockIdx.x * 256 + threadIdx.x;
    if (p < G_N) {
        int unit = p >> 2, gate = p & 3;
        bsum[p] = b_ih[gate * H_N + unit] + b_hh[gate * H_N + unit];
    }
}

__global__ void prep_zero(unsigned int* __restrict__ a32, float* __restrict__ cst,
                          float* __restrict__ acc)
{
    int idx = blockIdx.x * blockDim.x + threadIdx.x;
    if (idx < B_N * 1088) a32[idx] = 0u;
    if (idx < B_N * H_N) cst[idx] = 0.f;
    if (idx < 2 * 32 * B_N) acc[idx] = 0.f;
}

// ---------------- params ----------------
struct RParams {
    const float* mask;
    const float* bias_mat;
    const float* fc1_w;
    const float* fc1_b;
    const float* conv2_w;
    const float* conv2_b;
    const short* Wf;
    const short* Ain;
    short* Aout;
    const float* x;
    const float* ua;
    const float* bsum;
    float* accW;           // [32][4096] slot = n*2+hh
    float* accO;           // [32][4096]
    float* cstate;
    float* out;
};

// ---------------- ctx_step: sum 32 partial slots; softmax+context; out write ----------------
__global__ __launch_bounds__(256) void ctx_step(RParams P, int t)
{
    const int lane = threadIdx.x & 63;
    const int wave = threadIdx.x >> 6;
    const int row  = blockIdx.x * 4 + wave;

    float v = (lane < 32) ? P.accW[lane * B_N + row] : P.accO[(lane - 32) * B_N + row];
    #pragma unroll
    for (int off = 1; off <= 16; off <<= 1) v += __shfl_xor(v, off);
    float aW = __shfl(v, 0);
    float aO = __shfl(v, 32);

    if (t > 0 && lane == 0)
        P.out[row * T_N + (t - 1)] = (aO + P.conv2_b[0]) * P.mask[row * L_N + (t - 1)];

    if (t < T_N) {
        float w_a = aW + P.fc1_b[0];
        int l32 = lane & 31;
        float e = P.ua[row * L_N + l32] + w_a;
        e = (e > 0.f) ? e : 0.01f * e;
        e += P.bias_mat[row * L_N + l32];
        float mx = e;
        #pragma unroll
        for (int off = 16; off > 0; off >>= 1) mx = fmaxf(mx, __shfl_xor(mx, off, 32));
        float pexp = __expf(e - mx);
        float ssum = pexp;
        #pragma unroll
        for (int off = 16; off > 0; off >>= 1) ssum += __shfl_xor(ssum, off, 32);
        float p = pexp / ssum;
        int cc = (lane < C_N) ? lane : 0;
        const float* xrow = P.x + (size_t)row * (L_N * C_N) + cc;
        float ctx = 0.f;
        #pragma unroll
        for (int l = 0; l < L_N; ++l) {
            float al = __shfl(p, l);
            ctx += al * xrow[l * C_N];
        }
        if (lane < C_N) {
            int m128 = row >> 7, mt = (row & 127) >> 4, r = row & 15;
            int flane = r + 16 * (lane >> 3);
            short* base = P.Aout + (size_t)m128 * ABLK + mt * 512 + flane * 8 + (lane & 7);
            __hip_bfloat16 hi = __float2bfloat16(ctx);
            base[16 * CHSH] = bfbits(hi);
            base[33 * CHSH] = bfbits(__float2bfloat16(ctx - __bfloat162float(hi)));
        }
    }
}

// ---------------- gemm_cell_step: M=128, grid 512, 4-deep pinned prefetch ----------------
__global__ __launch_bounds__(256, 2) void gemm_cell_step(RParams P)
{
    __shared__ __align__(16) char smem[49152];   // gates 32KB @0; hasm 16KB @32768

    const int tid  = threadIdx.x;
    const int lane = tid & 63;
    const int wave = tid >> 6;
    const int bid  = blockIdx.x;       // 512
    const int xg = bid & 7, gg = bid >> 3;
    const int m  = (xg >> 1) * 8 + (gg & 7);
    const int n  = (xg & 1) * 8 + (gg >> 3);
    const int wm = wave >> 1, wn = wave & 1;

    const short* Af = P.Ain + (size_t)m * ABLK;
    const short* Wg = P.Wf  + (size_t)n * ABLK;
    const short* aB[4];
    const short* wB[4];
    #pragma unroll
    for (int i = 0; i < 4; ++i) {
        aB[i] = Af + ((wm * 4 + i) * 64 + lane) * 8;
        wB[i] = Wg + ((wn * 4 + i) * 64 + lane) * 8;
    }

    f32x4 acc[4][4];
    #pragma unroll
    for (int i = 0; i < 4; ++i)
        #pragma unroll
        for (int j = 0; j < 4; ++j)
            acc[i][j] = (f32x4){0.f, 0.f, 0.f, 0.f};

    s16x8 a0[4], w0[4], a1[4], w1[4], a2[4], w2[4], a3[4], w3[4];
    auto ldc = [&](int kc, s16x8 (&A)[4], s16x8 (&W)[4]) {
        int ka = (kc < CHA) ? kc : kc - CHA;
        int kw = (kc < 17) ? kc : kc - 17;
        #pragma unroll
        for (int i = 0; i < 4; ++i) A[i] = *(const s16x8*)(aB[i] + ka * CHSH);
        #pragma unroll
        for (int j = 0; j < 4; ++j) W[j] = *(const s16x8*)(wB[j] + kw * CHSH);
    };
    auto domm = [&](s16x8 (&A)[4], s16x8 (&W)[4]) {
        #pragma unroll
        for (int i = 0; i < 4; ++i)
            #pragma unroll
            for (int j = 0; j < 4; ++j)
                acc[i][j] = __builtin_amdgcn_mfma_f32_16x16x32_bf16(A[i], W[j], acc[i][j], 0, 0, 0);
    };

    ldc(0, a0, w0); ldc(1, a1, w1); ldc(2, a2, w2); ldc(3, a3, w3);
    __builtin_amdgcn_sched_barrier(0);
    for (int kc = 0; kc < 51; kc += 4) {
        domm(a0, w0); if (kc + 4 < 51) ldc(kc + 4, a0, w0);
        __builtin_amdgcn_sched_barrier(0);
        if (kc + 1 < 51) {
            domm(a1, w1); if (kc + 5 < 51) ldc(kc + 5, a1, w1);
            __builtin_amdgcn_sched_barrier(0);
        }
        if (kc + 2 < 51) {
            domm(a2, w2); if (kc + 6 < 51) ldc(kc + 6, a2, w2);
            __builtin_amdgcn_sched_barrier(0);
        }
        if (kc + 3 < 51) {
            domm(a3, w3); if (kc + 7 < 51) ldc(kc + 7, a3, w3);
            __builtin_amdgcn_sched_barrier(0);
        }
    }

    // ---- epilogue ----
    __syncthreads();
    float* gates = (float*)smem;                   // 128 x 64 f32
    short* hasm  = (short*)(smem + 32768);         // hi 8KB + lo 8KB
    #pragma unroll
    for (int hh = 0; hh < 2; ++hh) {
        // cstate prefetch (overlaps gates-LDS write + barrier)
        int u = tid & 15, rr = tid >> 4;
        int unit = n * 32 + hh * 16 + u;
        float cpre[8];
        #pragma unroll
        for (int it = 0; it < 8; ++it)
            cpre[it] = P.cstate[(size_t)(m * 128 + it * 16 + rr) * H_N + unit];
        f32x4 bsv = *(const f32x4*)(P.bsum + unit * 4);
        float f1v = P.fc1_w[unit];
        float c2v = P.conv2_w[unit];

        if (wn == hh) {
            #pragma unroll
            for (int i = 0; i < 4; ++i)
                #pragma unroll
                for (int j = 0; j < 4; ++j)
                    #pragma unroll
                    for (int r = 0; r < 4; ++r) {
                        int rowl = wm * 64 + i * 16 + (lane >> 4) * 4 + r;
                        int coll = j * 16 + (lane & 15);
                        gates[rowl * 64 + coll] = acc[i][j][r];
                    }
        }
        __syncthreads();
        {
            int flane = rr + 16 * (hh * 2 + (u >> 3));
            #pragma unroll
            for (int it = 0; it < 8; ++it) {
                int rowl = it * 16 + rr;
                int grow = m * 128 + rowl;
                f32x4 gv = *(const f32x4*)(gates + rowl * 64 + u * 4);
                float pi = gv.x + bsv.x;
                float pf = gv.y + bsv.y;
                float pg = gv.z + bsv.z;
                float po = gv.w + bsv.w;
                float c = sigmoidf_(pf) * cpre[it] + sigmoidf_(pi) * tanhf_(pg);
                P.cstate[(size_t)grow * H_N + unit] = c;
                float h = sigmoidf_(po) * tanhf_(c);
                __hip_bfloat16 hi = __float2bfloat16(h);
                hasm[it * 512 + flane * 8 + (u & 7)]        = bfbits(hi);
                hasm[4096 + it * 512 + flane * 8 + (u & 7)] = bfbits(__float2bfloat16(h - __bfloat162float(hi)));
                float wd = f1v * h, od = c2v * h;
                #pragma unroll
                for (int off = 8; off > 0; off >>= 1) {
                    wd += __shfl_xor(wd, off);
                    od += __shfl_xor(od, off);
                }
                if (u == 0) {
                    P.accW[(n * 2 + hh) * B_N + grow] = wd;
                    P.accO[(n * 2 + hh) * B_N + grow] = od;
                }
            }
        }
        __syncthreads();
    }
    short* dhi = P.Aout + (size_t)m * ABLK + (size_t)n * CHSH;
    short* dlo = P.Aout + (size_t)m * ABLK + (size_t)(17 + n) * CHSH;
    *(s16x8*)(dhi + tid * 16)     = *(const s16x8*)(hasm + tid * 16);
    *(s16x8*)(dhi + tid * 16 + 8) = *(const s16x8*)(hasm + tid * 16 + 8);
    *(s16x8*)(dlo + tid * 16)     = *(const s16x8*)(hasm + 4096 + tid * 16);
    *(s16x8*)(dlo + tid * 16 + 8) = *(const s16x8*)(hasm + 4096 + tid * 16 + 8);
}

extern "C" void kernel_launch(void* const* d_in, const int* in_sizes, int n_in,
                              void* d_out, int out_size, void* d_ws, size_t ws_size,
                              hipStream_t stream)
{
    float* out = (float*)d_out;
    if (ws_size < WS_NEED) { fill_out<<<512, 256, 0, stream>>>(out, 4000.f); return; }

    const float* input = (const float*)d_in[0];
    const float* mask  = (const float*)d_in[1];
    const float* biasm = (const float*)d_in[2];
    const float* w1    = (const float*)d_in[3];
    const float* b1    = (const float*)d_in[4];
    const float* cw    = (const float*)d_in[5];
    const float* cb    = (const float*)d_in[6];
    const float* w_ih  = (const float*)d_in[7];
    const float* w_hh  = (const float*)d_in[8];
    const float* b_ih  = (const float*)d_in[9];
    const float* b_hh  = (const float*)d_in[10];
    const float* fc1w  = (const float*)d_in[11];
    const float* fc1b  = (const float*)d_in[12];
    const float* c2w   = (const float*)d_in[13];
    const float* c2b   = (const float*)d_in[14];

    char* ws = (char*)d_ws;
    short* Wf = (short*)(ws + OFF_WF);
    short* A0 = (short*)(ws + OFF_AB);
    short* A1 = (short*)(ws + OFF_AB + AB_ONE);
    float* x    = (float*)(ws + OFF_X);
    float* ua   = (float*)(ws + OFF_UA);
    float* bsum = (float*)(ws + OFF_BS);
    float* accW = (float*)(ws + OFF_AC);
    float* accO = (float*)(ws + OFF_AC + ACC_HALF);
    float* cst  = (float*)(ws + OFF_CS);

    prep_x<<<(B_N * L_N) / 256, 256, 0, stream>>>(input, mask, w1, b1, cw, cb, x, ua);
    prep_wf<<<16 * CHA, 256, 0, stream>>>(w_ih, w_hh, Wf);
    prep_bs<<<(G_N + 255) / 256, 256, 0, stream>>>(b_ih, b_hh, bsum);
    prep_zero<<<(B_N * 1088 + 255) / 256, 256, 0, stream>>>((unsigned int*)A0, cst, accW);

    RParams P;
    P.mask = mask; P.bias_mat = biasm; P.fc1_w = fc1w; P.fc1_b = fc1b;
    P.conv2_w = c2w; P.conv2_b = c2b; P.Wf = Wf;
    P.x = x; P.ua = ua; P.bsum = bsum; P.accW = accW; P.accO = accO;
    P.cstate = cst; P.out = out;

    short* bufs[2] = { A0, A1 };
    for (int t = 0; t < T_N; ++t) {
        P.Ain  = bufs[t & 1];
        P.Aout = bufs[t & 1];
        ctx_step<<<B_N / 4, 256, 0, stream>>>(P, t);
        P.Ain  = bufs[t & 1];
        P.Aout = bufs[(t + 1) & 1];
        gemm_cell_step<<<512, 256, 0, stream>>>(P);
    }
    P.Ain = bufs[T_N & 1];
    P.Aout = bufs[T_N & 1];
    ctx_step<<<B_N / 4, 256, 0, stream>>>(P, T_N);
}